// Round 4
// baseline (326.244 us; speedup 1.0000x reference)
//
#include <hip/hip_runtime.h>

// CfCHead: B=64, S=2048, H=1024 sequential nonlinear scan. Round-4:
// transcendental elimination + packed fp32 (v_pk_fma_f32).
//  - x-only gate transcendentals replaced by polynomials evaluated on
//    float2 pairs (deg-8 Taylor e^z, |z|<=1.6; deg-9 odd sigmoid poly),
//    packed via __builtin_elementwise_fma -> v_pk_fma_f32 (full rate).
//  - En = e^{-n} tracked multiplicatively: En *= cubic(delta),
//    delta = 0.03 - 0.01*(i+f+o); kills exp2(m) (err <= 9e-6/step).
//  - only exp2(C) + rcp (sigmoid of unbounded c) remain per step.
//  - consumer waves preload their 32 proj_w values into registers (pattern
//    is thread-static) -> no pw LDS reads in the loop.
// Structure from round-3 (passed, 0 bank conflicts): 256 blocks x 512 thr,
// waves 0-3 produce 256 chains, waves 4-7 reduce; 1 barrier/chunk,
// double-buffered h in LDS (stride 17).

typedef float v2f __attribute__((ext_vector_type(2)));

#define Bv   64
#define Sv   2048
#define Hv   1024
#define TPB  256
#define NT   512
#define CH   16
#define HSTR 17
#define HBUF (TPB * HSTR)

#define NL2E (-1.44269504088896340736f)

__device__ __forceinline__ float fexp2(float x) { return __builtin_amdgcn_exp2f(x); }
__device__ __forceinline__ float frcp(float x)  { return __builtin_amdgcn_rcpf(x); }
__device__ __forceinline__ v2f   vfma(v2f a, v2f b, v2f c) {
    return __builtin_elementwise_fma(a, b, c);
}
__device__ __forceinline__ v2f splat(float s) { v2f r; r.x = s; r.y = s; return r; }

// e^z, deg-8 Taylor (|z| <= 1.2 in practice; rel err <= 5e-5, tails to 1.6 ok)
__device__ __forceinline__ v2f exp_poly(v2f z) {
    v2f p = vfma(z, splat(2.4801587e-5f), splat(1.9841270e-4f));
    p = vfma(p, z, splat(1.3888889e-3f));
    p = vfma(p, z, splat(8.3333333e-3f));
    p = vfma(p, z, splat(4.1666667e-2f));
    p = vfma(p, z, splat(1.6666667e-1f));
    p = vfma(p, z, splat(0.5f));
    p = vfma(p, z, splat(1.0f));
    p = vfma(p, z, splat(1.0f));
    return p;
}

// scale*sigmoid(z) = A + z*Q(z^2), deg-9 odd (coeffs pre-scaled by caller)
__device__ __forceinline__ v2f sig_poly(v2f z, float q4, float q3, float q2,
                                        float q1, float q0, float A) {
    const v2f w = z * z;
    v2f Q = vfma(w, splat(q4), splat(q3));
    Q = vfma(Q, w, splat(q2));
    Q = vfma(Q, w, splat(q1));
    Q = vfma(Q, w, splat(q0));
    return vfma(z, Q, splat(A));
}

// out[b*S*2 + t*2 + k] = proj_b[k]  (clears 0xAA poison; scan atomically adds)
__global__ __launch_bounds__(256) void init_out(const float* __restrict__ proj_b,
                                                float* __restrict__ out) {
    int i = blockIdx.x * 256 + threadIdx.x;
    out[i] = proj_b[i & 1];
}

__global__ __launch_bounds__(NT, 1) void cfc_scan(
    const float* __restrict__ x_codes,
    const float* __restrict__ Wi_w, const float* __restrict__ Wi_b,
    const float* __restrict__ Wf_w, const float* __restrict__ Wf_b,
    const float* __restrict__ Wo_w, const float* __restrict__ Wo_b,
    const float* __restrict__ Wg_w, const float* __restrict__ Wg_b,
    const float* __restrict__ Wl_w, const float* __restrict__ Wl_b,
    const float* __restrict__ proj_w,
    const float* __restrict__ n_init,
    float* __restrict__ out)
{
    __shared__ float hlds[2 * HBUF];    // double-buffered raw h, [par][j][u]

    const int b   = blockIdx.x >> 2;
    const int q   = blockIdx.x & 3;
    const int tid = threadIdx.x;

    const float* __restrict__ xrow = x_codes + b * Sv;
    float* __restrict__ orow = out + b * (Sv * 2);

    // ---- consumer setup (waves 4-7): preload proj_w pattern to registers ----
    const int ct   = tid - TPB;
    const int rk   = (ct >> 7) & 1;
    const int rt   = (ct >> 3) & 15;
    const int rseg = ct & 7;
    float pwreg[32];
    if (tid >= TPB) {
        const float* __restrict__ pwsrc = proj_w + rk * Hv + q * TPB;
        #pragma unroll
        for (int i2 = 0; i2 < 32; ++i2) {
            const int jj = rseg * 32 + ((i2 + 4 * rseg) & 31);
            pwreg[i2] = pwsrc[jj];
        }
    }

    // ---- producer setup (waves 0-3): fold affine maps; e-domain (no L2E) ----
    v2f wip = splat(0.f), bip = splat(0.f), wfp = splat(0.f), bfp = splat(0.f);
    v2f wop = splat(0.f), bop = splat(0.f), wgp = splat(0.f), bgp = splat(0.f);
    v2f wlp = splat(0.f), blp = splat(0.f);
    float En = 0.f, C = 0.f, h = 0.f;
    if (tid < TPB) {
        const int j = q * TPB + tid;
        const float wi = Wi_w[j], bi = Wi_b[j];
        const float wf = Wf_w[j], bf = Wf_b[j];
        const float wo = Wo_w[j], bo = Wo_b[j];
        const float wg = Wg_w[j], bg = Wg_b[j];
        const float wl = Wl_w[j], bl = Wl_b[j];
        // pre = ((code-65)/100)*w + b = code*(w/100) + (b - 0.65w)
        wip = splat(wi * 0.01f); bip = splat(fmaf(-0.65f, wi, bi));
        wfp = splat(wf * 0.01f); bfp = splat(fmaf(-0.65f, wf, bf));
        wop = splat(wo * 0.01f); bop = splat(fmaf(-0.65f, wo, bo));
        wgp = splat(wg * 0.01f); bgp = splat(fmaf(-0.65f, wg, bg));
        wlp = splat(wl * 0.01f); blp = splat(fmaf(-0.65f, wl, bl));
        En = fexp2(n_init[j] * NL2E);   // e^{-n_0}
    }

    int par = 0;
    for (int t0 = 0; t0 < Sv; t0 += CH, par ^= 1) {
        if (tid < TPB) {
            v2f GfA[CH / 2], GigA[CH / 2], GoA[CH / 2], GsA[CH / 2], IlA[CH / 2];
            // -- x-only gates: all-polynomial, packed fp32, fully parallel --
            #pragma unroll
            for (int up = 0; up < CH / 2; ++up) {
                v2f xc; xc.x = xrow[t0 + 2 * up]; xc.y = xrow[t0 + 2 * up + 1];
                const v2f zi = vfma(xc, wip, bip);
                const v2f zf = vfma(xc, wfp, bfp);
                const v2f zo = vfma(xc, wop, bop);
                const v2f zg = vfma(xc, wgp, bgp);
                const v2f zl = vfma(xc, wlp, blp);
                const v2f Gi = exp_poly(zi);          // e^{pre_i}
                const v2f Gf = exp_poly(zf);          // e^{pre_f}
                const v2f Go = exp_poly(zo);          // e^{pre_o}
                // -L2E * sigmoid(pre_g)
                const v2f sg = sig_poly(zg, -3.0811453e-5f, 3.0414935e-4f,
                                        -3.0056147e-3f, 3.0056147e-2f,
                                        -0.36067376f, -0.72134752f);
                // 0.01 * sigmoid(pre_l)
                const v2f tl = sig_poly(zl, 2.1356902e-7f, -2.1081349e-6f,
                                        2.0833333e-5f, -2.0833333e-4f,
                                        2.5e-3f, 5.0e-3f);
                GfA[up]  = Gf;
                GigA[up] = Gi * sg;
                GoA[up]  = Go;
                GsA[up]  = (Gi + Gf) + Go;
                // 1/(1+t) ~= 1 - t + t^2  (t <= 0.01, err <= 1e-6)
                IlA[up]  = vfma(tl - splat(1.0f), tl, splat(1.0f));
            }
            // -- serial recurrence: exp2(C) + rcp are the only transcendentals --
            float* __restrict__ hrow = &hlds[par * HBUF + tid * HSTR];
            #pragma unroll
            for (int u = 0; u < CH; ++u) {
                const int hp = u >> 1, sl = u & 1;
                const float Gfu  = GfA[hp][sl];
                const float Gigu = GigA[hp][sl];
                const float Gou  = GoA[hp][sl];
                const float Gsu  = GsA[hp][sl];
                const float Ilu  = IlA[hp][sl];
                const float ef = Gfu * En;                      // f_t
                C = fmaf(ef, C, Gigu * En);                     // C = -L2E*c
                const float e2C  = fexp2(C);                    // e^{-c}
                const float sc01 = frcp(fmaf(e2C, 100.f, 100.f)); // 0.01*sig(c)
                h = fmaf(Gou * En, sc01, h) * Ilu;
                hrow[u] = h;
                // En *= e^{delta}, delta = 0.03 - 0.01*(i+f+o); cubic Taylor
                const float d = fmaf(Gsu * En, -0.01f, 0.03f);
                float p = fmaf(d, 0.16666667f, 0.5f);
                p = fmaf(d, p, 1.0f);
                p = fmaf(d, p, 1.0f);
                En = En * p;
            }
        }
        __syncthreads();   // producers publish h[par]; consumers reduce it
        if (tid >= TPB) {
            const float* __restrict__ hb = &hlds[par * HBUF];
            float sum = 0.0f;
            #pragma unroll
            for (int i2 = 0; i2 < 32; ++i2) {
                const int jj = rseg * 32 + ((i2 + 4 * rseg) & 31); // 2-way banks
                sum = fmaf(hb[jj * HSTR + rt], pwreg[i2], sum);
            }
            sum += __shfl_xor(sum, 1, 64);
            sum += __shfl_xor(sum, 2, 64);
            sum += __shfl_xor(sum, 4, 64);
            if (rseg == 0) atomicAdd(&orow[(t0 + rt) * 2 + rk], sum);
        }
    }
}

extern "C" void kernel_launch(void* const* d_in, const int* in_sizes, int n_in,
                              void* d_out, int out_size, void* d_ws, size_t ws_size,
                              hipStream_t stream) {
    const float* x_codes = (const float*)d_in[0];
    const float* Wi_w = (const float*)d_in[1];
    const float* Wi_b = (const float*)d_in[2];
    const float* Wf_w = (const float*)d_in[3];
    const float* Wf_b = (const float*)d_in[4];
    const float* Wo_w = (const float*)d_in[5];
    const float* Wo_b = (const float*)d_in[6];
    const float* Wg_w = (const float*)d_in[7];
    const float* Wg_b = (const float*)d_in[8];
    const float* Wl_w = (const float*)d_in[9];
    const float* Wl_b = (const float*)d_in[10];
    const float* proj_w = (const float*)d_in[11];
    const float* proj_b = (const float*)d_in[12];
    const float* n_init = (const float*)d_in[13];
    float* out = (float*)d_out;

    init_out<<<out_size / 256, 256, 0, stream>>>(proj_b, out);
    cfc_scan<<<Bv * (Hv / TPB), NT, 0, stream>>>(
        x_codes, Wi_w, Wi_b, Wf_w, Wf_b, Wo_w, Wo_b, Wg_w, Wg_b, Wl_w, Wl_b,
        proj_w, n_init, out);
}